// Round 4
// baseline (150.180 us; speedup 1.0000x reference)
//
#include <hip/hip_runtime.h>

// out[b] = M0 @ M1 @ ... @ M95  (4x4 fp32 chain per batch, left-to-right)
// Layout: mats[B][96][4][4] row-major fp32 = 384 float4 = 6144 B per batch.
//
// R4: maximal read contiguity via associativity.
//   One WAVE per batch: quad q computes segment product P_q = M_{6q}..M_{6q+5}
//   (left-to-right, in registers, DPP quad-broadcasts), then a 4-level
//   __shfl tree combines P_0*P_1*...*P_15 in order. The wave's 6 load
//   instructions cover the batch's entire 6144 B CONTIGUOUS; adjacent waves
//   read adjacent 6 KB regions -> sequential DRAM bursts (same class as the
//   6.6 TB/s fill kernels). No LDS. Each wave ping-pongs 4 batches through
//   two register buffers to hide HBM latency intra-wave.

template <int CTRL>
__device__ __forceinline__ float dpp_mov(float x) {
    int xi = __builtin_bit_cast(int, x);
    int r = __builtin_amdgcn_update_dpp(0, xi, CTRL, 0xF, 0xF, true);
    return __builtin_bit_cast(float, r);
}

// Broadcast lane J (within each quad) of all 4 components of m.
template <int J>
__device__ __forceinline__ float4 quad_bcast(float4 m) {
    constexpr int C = J * 0x55;  // quad_perm:[J,J,J,J]
    float4 r;
    r.x = dpp_mov<C>(m.x);
    r.y = dpp_mov<C>(m.y);
    r.z = dpp_mov<C>(m.z);
    r.w = dpp_mov<C>(m.w);
    return r;
}

// acc = vl.x*a0 + vl.y*a1 + vl.z*a2 + vl.w*a3   (row-vector times matrix rows)
__device__ __forceinline__ float4 rows_combine(float4 vl, float4 a0, float4 a1,
                                               float4 a2, float4 a3) {
    float4 acc;
    acc.x = vl.x * a0.x; acc.y = vl.x * a0.y; acc.z = vl.x * a0.z; acc.w = vl.x * a0.w;
    acc.x = fmaf(vl.y, a1.x, acc.x); acc.y = fmaf(vl.y, a1.y, acc.y);
    acc.z = fmaf(vl.y, a1.z, acc.z); acc.w = fmaf(vl.y, a1.w, acc.w);
    acc.x = fmaf(vl.z, a2.x, acc.x); acc.y = fmaf(vl.z, a2.y, acc.y);
    acc.z = fmaf(vl.z, a2.z, acc.z); acc.w = fmaf(vl.z, a2.w, acc.w);
    acc.x = fmaf(vl.w, a3.x, acc.x); acc.y = fmaf(vl.w, a3.y, acc.y);
    acc.z = fmaf(vl.w, a3.z, acc.z); acc.w = fmaf(vl.w, a3.w, acc.w);
    return acc;
}

// v = this lane's row of the carry; m = this lane's row of M (quad-local).
__device__ __forceinline__ float4 row_times_mat(float4 v, float4 m) {
    return rows_combine(v, quad_bcast<0>(m), quad_bcast<1>(m),
                        quad_bcast<2>(m), quad_bcast<3>(m));
}

__device__ __forceinline__ float4 shfl4(float4 v, int src) {
    float4 r;
    r.x = __shfl(v.x, src);
    r.y = __shfl(v.y, src);
    r.z = __shfl(v.z, src);
    r.w = __shfl(v.w, src);
    return r;
}

// Load this lane's 6 segment rows: row r of M_{6q+j}, j=0..5.
// base points at mats + b*384 + q*24 + r  -> element j at +4j.
__device__ __forceinline__ void load_mats(float4 dst[6], const float4* base) {
#pragma unroll
    for (int j = 0; j < 6; ++j) dst[j] = base[4 * j];
}

// Segment chain + 4-level tree. Returns this lane's row of the full product.
__device__ __forceinline__ float4 process(const float4 m[6], int q, int r) {
    float4 v = m[0];
#pragma unroll
    for (int j = 1; j < 6; ++j) v = row_times_mat(v, m[j]);
    // v = row r of P_q. Tree: combine pairs of quad groups, in chain order.
#pragma unroll
    for (int L = 0; L < 4; ++L) {
        const int lo = ((q & ~(1 << L)) << 2) + r;  // lane holding row r of P_lo
        const int hi = ((q | (1 << L)) << 2);       // lanes holding rows of P_hi
        float4 vl = shfl4(v, lo);
        float4 a0 = shfl4(v, hi + 0);
        float4 a1 = shfl4(v, hi + 1);
        float4 a2 = shfl4(v, hi + 2);
        float4 a3 = shfl4(v, hi + 3);
        v = rows_combine(vl, a0, a1, a2, a3);       // row r of P_lo @ P_hi
    }
    return v;
}

__global__ __launch_bounds__(256)
void chainmul_seg(const float4* __restrict__ mats, float4* __restrict__ out) {
    const int lane = threadIdx.x & 63;
    const int wg   = (blockIdx.x * 256 + threadIdx.x) >> 6;  // global wave id
    const int q    = lane >> 2;   // segment / quad id
    const int r    = lane & 3;    // row this lane owns
    const int b0   = wg * 4;      // 4 batches per wave, ping-ponged

    const float4* base = mats + (size_t)b0 * 384 + q * 24 + r;

    float4 mA[6], mB[6];
    load_mats(mA, base);             // batch b0+0
    load_mats(mB, base + 384);       // batch b0+1

    float4 v = process(mA, q, r);
    load_mats(mA, base + 768);       // batch b0+2
    if (q == 0) out[(size_t)(b0 + 0) * 4 + r] = v;

    v = process(mB, q, r);
    load_mats(mB, base + 1152);      // batch b0+3
    if (q == 0) out[(size_t)(b0 + 1) * 4 + r] = v;

    v = process(mA, q, r);
    if (q == 0) out[(size_t)(b0 + 2) * 4 + r] = v;

    v = process(mB, q, r);
    if (q == 0) out[(size_t)(b0 + 3) * 4 + r] = v;
}

extern "C" void kernel_launch(void* const* d_in, const int* in_sizes, int n_in,
                              void* d_out, int out_size, void* d_ws, size_t ws_size,
                              hipStream_t stream) {
    const float4* mats = (const float4*)d_in[0];
    float4* out = (float4*)d_out;

    const int B = in_sizes[0] / (96 * 16);   // 131072
    const int grid = B / 16;                 // 16 batches per 256-thread block
    hipLaunchKernelGGL(chainmul_seg, dim3(grid), dim3(256), 0, stream,
                       mats, out);
}